// Round 15
// baseline (108.883 us; speedup 1.0000x reference)
//
#include <hip/hip_runtime.h>

// Sizes (fixed for this problem)
constexpr int B  = 2,  CIN = 2,  H = 64, W = 64, T = 350;
constexpr int C1 = 8;                       // conv1 out channels
constexpr int TO = 700, HO = 128, WO = 64;
constexpr int HW = H * W;                   // 4096

#define DEC 0.05000000074505806f            // (float)(1.0 - 0.95)

__device__ __forceinline__ float rfl(float x) {
  return __int_as_float(
      __builtin_amdgcn_readfirstlane(__float_as_int(x)));
}

// ---------------------------------------------------------------------------
// Kernel 0: transpose x [B,2,H,W,T] -> xT [B,2,T,H,W] so conv reads coalesce.
// ---------------------------------------------------------------------------
__global__ void __launch_bounds__(256) transpose_kernel(
    const float* __restrict__ x, float* __restrict__ xT) {
  __shared__ float tile[64][65];
  int bid   = blockIdx.x;
  int tTile = bid % 6;            // 6 tiles of 64 cover T=350
  int slice = bid / 6;            // (b*2+ci)*64 + h
  int h  = slice % H;
  int bc = slice / H;             // b*2+ci
  int t0 = tTile * 64;
  int tx = threadIdx.x & 63;
  int tz = threadIdx.x >> 6;      // 0..3

  const float* src = x + ((long)bc * H + h) * (long)(W * T);
#pragma unroll
  for (int i = 0; i < 16; ++i) {
    int w = tz * 16 + i;
    int t = t0 + tx;
    tile[w][tx] = (t < T) ? src[(long)w * T + t] : 0.0f;
  }
  __syncthreads();
  float* dst = xT + ((long)bc * T) * HW + h * 64;
#pragma unroll
  for (int i = 0; i < 16; ++i) {
    int tl = tz * 16 + i;
    int t  = t0 + tl;
    if (t < T) dst[(long)t * HW + tx] = tile[tx][tl];
  }
}

// ---------------------------------------------------------------------------
// async global->LDS, 16 bytes per lane (wave-uniform LDS base + lane*16)
// ---------------------------------------------------------------------------
__device__ __forceinline__ void gload_lds16(const float* g, float* l) {
  __builtin_amdgcn_global_load_lds(
      (const __attribute__((address_space(1))) unsigned int*)g,
      (__attribute__((address_space(3))) unsigned int*)l, 16, 0, 0);
}

// ---------------------------------------------------------------------------
// FUSED kernel: conv1(5x5)+relu+LIF1+delta  ==LDS==>  deconv(2x2,s2)+relu+
// conv2(1x1)+LIF2 -> out.  NO d8 intermediate, NO stage2 dispatch.
// Block 512 = conv roles (cp 0..3)x(hs 0..1)x(w 0..63)  AND  LIF2 roles
// (hq 0..3)x(o 0..1)x(wp 0..63): thread owns out row (b, o, hp=4*h2+hq, wp).
// Per superstep k (S=10): conv writes delta spikes into st[k&1] (2h x 64w x
// 8ci bytes per t); LIF2 consumes st[(k-1)&1] (published at barrier1),
// streaming float2 {s'(2t),s'(2t+1)} to out -- each thread writes its row
// sequentially so L2 merges into full lines.
// Warm-up 25 conv steps (LIF1 converged by +15 [0.05^15~3e-20]; LIF2 then
// sees >=16 correct t' before 2*tstore, residual 0.05^18 ~ 4e-24 << ulp).
// LIF2 weights are wave-uniform -> readfirstlane into SGPRs (VGPR relief).
// LDS: 64KB input dbuf + 20KB st dbuf = 84KB.
// ---------------------------------------------------------------------------
__global__ void __launch_bounds__(512) fused_kernel(
    const float* __restrict__ xT, const float* __restrict__ w1,
    const float* __restrict__ b1, const float* __restrict__ dwv,
    const float* __restrict__ dbv, const float* __restrict__ cwv,
    const float* __restrict__ cbv, float* __restrict__ out) {
  __shared__ float buf[2][128 * 64];                      // 2 x 32 KiB
  __shared__ __align__(8) unsigned char st[2][10][1024];  // 20 KiB spikes
  const int tid = threadIdx.x;
  const int bid = blockIdx.x;
  const int chunk = bid & 3;
  const int h2 = (bid >> 2) & 31;
  const int b  = bid >> 7;
  const int h0 = h2 * 2;
  const int w  = tid & 63;
  const int hs = (tid >> 6) & 1;            // conv: which h of the pair
  const int cp = tid >> 7;                  // conv: co-pair 0..3
  const int h  = h0 + hs;
  const int wid = tid >> 6;                 // wave id 0..7

  // chunk c of 4: stored [90c, te); 25-step warm-up (LIF2-safe).
  const int tstore = chunk * 90;
  const int ts     = chunk ? tstore - 25 : 0;     // multiple of 5
  const int te     = tstore + 90 < T ? tstore + 90 : T;
  const int nsup   = (te - ts + 9) / 10;

  // ---- conv weights (per-thread VGPR; OOB-h taps zeroed) ----
  float wt[2][2][5][5];
#pragma unroll
  for (int ci = 0; ci < 2; ++ci)
#pragma unroll
    for (int dh = 0; dh < 5; ++dh) {
      int hh = h + dh - 2;
      bool hv = (hh >= 0) && (hh < H);
#pragma unroll
      for (int dt = 0; dt < 5; ++dt) {
        wt[0][ci][dt][dh] = hv ? w1[(((cp*2+0) * 2 + ci) * 5 + dt) * 5 + dh] : 0.0f;
        wt[1][ci][dt][dh] = hv ? w1[(((cp*2+1) * 2 + ci) * 5 + dt) * 5 + dh] : 0.0f;
      }
    }
  float bias0 = b1[cp*2], bias1 = b1[cp*2+1];

  // ---- LIF2 role params (all wave-uniform -> scalars) ----
  const int hq = __builtin_amdgcn_readfirstlane(tid >> 7);        // 0..3
  const int oo = __builtin_amdgcn_readfirstlane((tid >> 6) & 1);  // 0..1
  const int hs2 = hq >> 1;                  // which st h-sub to read
  const int kh  = 1 - (hq & 1);
  float dk0[2][8], dk1[2][8];
#pragma unroll
  for (int c = 0; c < 2; ++c)
#pragma unroll
    for (int ci = 0; ci < 8; ++ci) {
      dk0[c][ci] = rfl(dwv[((c * 8 + ci) * 2 + 0) * 2 + kh]);
      dk1[c][ci] = rfl(dwv[((c * 8 + ci) * 2 + 1) * 2 + kh]);
    }
  const float db0 = rfl(dbv[0]), db1 = rfl(dbv[1]);
  const float cwa = rfl(cwv[oo * 2]), cwb = rfl(cwv[oo * 2 + 1]);
  const float cbo = rfl(cbv[oo]);
  float* const orow =
      out + ((long)((b * 2 + oo) * HO + (h0 * 2 + hq)) * WO + w) * (long)TO;

  // ---- staging descriptors: 4 issues x 32 rows; row r = j*12+ci*6+dhh ----
  int cdesc[4];
#pragma unroll
  for (int i = 0; i < 4; ++i) {
    int r = (tid >> 4) + 32 * i;
    if (r > 119) r = 119;                   // clamp SOURCE; dest rows <=127 ok
    int j   = r / 12;
    int rem = r - j * 12;
    int ci  = rem / 6;
    int dhh = rem - ci * 6;
    int hh = h0 + dhh - 2;
    int hc = hh < 0 ? 0 : (hh > H - 1 ? H - 1 : hh);
    cdesc[i] = (((b * 2 + ci) * T) * HW + hc * 64 + (tid & 15) * 4) | (j << 27);
  }

  // Prologue: stage buf[0] (taus ts+3 .. ts+12).
#pragma unroll
  for (int i = 0; i < 4; ++i) {
    int tau = ts + 3 + (cdesc[i] >> 27);
    if (tau > T - 1) tau = T - 1;
    gload_lds16(xT + (long)(cdesc[i] & 0x07ffffff) + (long)tau * HW,
                &buf[0][(i * 32 + wid * 4) * 64]);
  }

  // Window init (taus ts-2..ts+2) from global; slot = tau % 5 (ts%5==0).
  float win[2][5][5];
#pragma unroll
  for (int ci = 0; ci < 2; ++ci)
#pragma unroll
    for (int dh = 0; dh < 5; ++dh) {
      int hh = h + dh - 2;
      int hc = hh < 0 ? 0 : (hh > H - 1 ? H - 1 : hh);
      const float* bp = xT + ((long)((b * 2 + ci) * T)) * HW + hc * 64 + w;
      win[ci][dh][3] = (ts >= 2) ? bp[(long)(ts - 2) * HW] : 0.0f;
      win[ci][dh][4] = (ts >= 1) ? bp[(long)(ts - 1) * HW] : 0.0f;
      win[ci][dh][0] = bp[(long)(ts + 0) * HW];
      win[ci][dh][1] = bp[(long)(ts + 1) * HW];
      win[ci][dh][2] = bp[(long)(ts + 2) * HW];
    }

  asm volatile("s_waitcnt vmcnt(0)" ::: "memory");
  __builtin_amdgcn_s_barrier();
  asm volatile("" ::: "memory");

  const int stw = (hs * 64 + w) * 4 + cp;   // conv ushort slot in st row

  float y0 = 0.0f, y1 = 0.0f, sp0 = 0.0f, sp1 = 0.0f;  // LIF1 state (2 co)
  float y2 = 0.0f;                                     // LIF2 state (1 row)

  // LIF2 pass over st[kprev&1] (covers t in [ts+10*kprev, +10)).
  auto lif2pass = [&](int kprev) {
    const unsigned char* stp = &st[kprev & 1][0][0];
    const int tb = ts + 10 * kprev;
#pragma unroll
    for (int u = 0; u < 10; ++u) {
      int t = tb + u;
      uint2 dvv = *reinterpret_cast<const uint2*>(
          stp + u * 1024 + (hs2 * 64 + w) * 8);
      float dv[8];
#pragma unroll
      for (int ci = 0; ci < 4; ++ci) {
        dv[ci]     = (float)(signed char)((dvv.x >> (8 * ci)) & 0xff);
        dv[ci + 4] = (float)(signed char)((dvv.y >> (8 * ci)) & 0xff);
      }
      // t' = 2t  (kt=1)
      float v0 = db0, v1 = db1;
#pragma unroll
      for (int ci = 0; ci < 8; ++ci) {
        v0 = fmaf(dv[ci], dk1[0][ci], v0);
        v1 = fmaf(dv[ci], dk1[1][ci], v1);
      }
      v0 = fmaxf(v0, 0.0f); v1 = fmaxf(v1, 0.0f);
      float uo = fmaf(cwa, v0, fmaf(cwb, v1, cbo));
      y2 = fmaf(DEC, y2, uo);
      float s0 = (y2 >= 1.0f) ? 1.0f : 0.0f;
      y2 = (s0 != 0.0f) ? 0.0f : y2;
      // t' = 2t+1  (kt=0)
      v0 = db0; v1 = db1;
#pragma unroll
      for (int ci = 0; ci < 8; ++ci) {
        v0 = fmaf(dv[ci], dk0[0][ci], v0);
        v1 = fmaf(dv[ci], dk0[1][ci], v1);
      }
      v0 = fmaxf(v0, 0.0f); v1 = fmaxf(v1, 0.0f);
      uo = fmaf(cwa, v0, fmaf(cwb, v1, cbo));
      y2 = fmaf(DEC, y2, uo);
      float s1 = (y2 >= 1.0f) ? 1.0f : 0.0f;
      y2 = (s1 != 0.0f) ? 0.0f : y2;
      if (t >= tstore && t < te) {
        float2 vv; vv.x = s0; vv.y = s1;
        *reinterpret_cast<float2*>(orow + 2 * t) = vv;
      }
    }
  };

  for (int k = 0; k < nsup; ++k) {
    // barrier1: publish st[(k-1)&1]; prior readers of buf[(k+1)&1] done.
    asm volatile("s_waitcnt lgkmcnt(0)" ::: "memory");
    __builtin_amdgcn_s_barrier();
    asm volatile("" ::: "memory");

    if (k + 1 < nsup) {
      int bs = ts + 3 + 10 * (k + 1);
      float* nb = &buf[(k + 1) & 1][0];
#pragma unroll
      for (int i = 0; i < 4; ++i) {
        int tau = bs + (cdesc[i] >> 27);
        if (tau > T - 1) tau = T - 1;
        gload_lds16(xT + (long)(cdesc[i] & 0x07ffffff) + (long)tau * HW,
                    nb + (i * 32 + wid * 4) * 64);
      }
      asm volatile("s_waitcnt vmcnt(4)" ::: "memory");  // buf[k&1] arrived
    } else {
      asm volatile("s_waitcnt vmcnt(0)" ::: "memory");
    }
    asm volatile("s_waitcnt lgkmcnt(0)" ::: "memory");
    __builtin_amdgcn_s_barrier();           // barrier2: buf[k&1] ready
    asm volatile("" ::: "memory");

    float* lb = &buf[k & 1][0];
    {
      // zero rows whose tau >= T (final supersteps of last chunk only)
      int bufstart = ts + 3 + 10 * k;
      int rz0 = (T - bufstart) * 12;
      if (rz0 < 120) {
        if (rz0 < 0) rz0 = 0;
        for (int r = rz0 + wid; r < 120; r += 8) lb[r * 64 + w] = 0.0f;
        asm volatile("s_waitcnt lgkmcnt(0)" ::: "memory");
        __builtin_amdgcn_s_barrier();
        asm volatile("" ::: "memory");
      }
    }

    // LIF2 over last superstep's spikes (st[(k-1)&1], published at barrier1).
    if (k > 0) lif2pass(k - 1);

    // conv + LIF1 + delta -> st[k&1]
    unsigned short* stks = reinterpret_cast<unsigned short*>(&st[k & 1][0][0]);
    const int t0s = ts + 10 * k;
    for (int jj = 0; jj < 2; ++jj) {
#pragma unroll
      for (int u = 0; u < 5; ++u) {
        const int j5 = jj * 5;
        int t = t0s + j5 + u;
        float a0q0 = 0.f, a0q1 = 0.f, a0q2 = 0.f, a0q3 = 0.f;
        float a1q0 = 0.f, a1q1 = 0.f, a1q2 = 0.f, a1q3 = 0.f;
#pragma unroll
        for (int ci = 0; ci < 2; ++ci)
#pragma unroll
          for (int dt = 0; dt < 5; ++dt) {
            const int slot = (u + dt + 3) % 5;
#pragma unroll
            for (int dh = 0; dh < 5; ++dh) {
              const int q = (ci * 25 + dt * 5 + dh) & 3;
              float tap = win[ci][dh][slot];
              float p0 = tap * wt[0][ci][dt][dh];
              float p1 = tap * wt[1][ci][dt][dh];
              if (q == 0)      { a0q0 += p0; a1q0 += p1; }
              else if (q == 1) { a0q1 += p0; a1q1 += p1; }
              else if (q == 2) { a0q2 += p0; a1q2 += p1; }
              else             { a0q3 += p0; a1q3 += p1; }
            }
          }
        float a0 = fmaxf(((a0q0 + a0q1) + (a0q2 + a0q3)) + bias0, 0.0f);
        float a1 = fmaxf(((a1q0 + a1q1) + (a1q2 + a1q3)) + bias1, 0.0f);
        y0 = fmaf(DEC, y0, a0);
        y1 = fmaf(DEC, y1, a1);
        float s0 = (y0 >= 1.0f) ? 1.0f : 0.0f;
        float s1 = (y1 >= 1.0f) ? 1.0f : 0.0f;
        int d0 = (int)(s0 - sp0) & 0xff;
        int d1 = (int)(s1 - sp1) & 0xff;
        unsigned short val = (unsigned short)(d0 | (d1 << 8));
        if (t == 0) val = 0;
        stks[(j5 + u) * 512 + stw] = val;
        sp0 = s0; sp1 = s1;
        y0 = (s0 != 0.0f) ? 0.0f : y0;
        y1 = (s1 != 0.0f) ? 0.0f : y1;
        // slide: tau = t+3 at row ((j5+u)*12 + ci*6 + dh + hs)
        const int slot2 = (u + 3) % 5;
#pragma unroll
        for (int ci = 0; ci < 2; ++ci)
#pragma unroll
          for (int dh = 0; dh < 5; ++dh)
            win[ci][dh][slot2] =
                lb[((j5 + u) * 12 + ci * 6 + dh + hs) * 64 + w];
      }
    }
  }

  // Epilogue: LIF2 over the final superstep's spikes.
  asm volatile("s_waitcnt lgkmcnt(0)" ::: "memory");
  __builtin_amdgcn_s_barrier();
  asm volatile("" ::: "memory");
  lif2pass(nsup - 1);
}

// ---------------------------------------------------------------------------
extern "C" void kernel_launch(void* const* d_in, const int* in_sizes, int n_in,
                              void* d_out, int out_size, void* d_ws, size_t ws_size,
                              hipStream_t stream) {
  const float* x  = (const float*)d_in[0];
  const float* w1 = (const float*)d_in[1];
  const float* b1 = (const float*)d_in[2];
  const float* dw = (const float*)d_in[3];
  const float* db = (const float*)d_in[4];
  const float* cw = (const float*)d_in[5];
  const float* cb = (const float*)d_in[6];
  float* out = (float*)d_out;

  float* xT = (float*)d_ws;                                   // 22.94 MB

  // 1) transpose x -> xT
  transpose_kernel<<<dim3(B * CIN * H * 6), dim3(256), 0, stream>>>(x, xT);
  // 2) fully fused conv1+LIF1+delta+deconv+conv2+LIF2 -> out
  fused_kernel<<<dim3(B * 32 * 4), dim3(512), 0, stream>>>(
      xT, w1, b1, dw, db, cw, cb, out);
}

// Round 16
// 105.091 us; speedup vs baseline: 1.0361x; 1.0361x over previous
//
#include <hip/hip_runtime.h>

// Sizes (fixed for this problem)
constexpr int B  = 2,  CIN = 2,  H = 64, W = 64, T = 350;
constexpr int C1 = 8;                       // conv1 out channels
constexpr int TO = 700, HO = 128, WO = 64;
constexpr int HW = H * W;                   // 4096

#define DEC 0.05000000074505806f            // (float)(1.0 - 0.95)

// ---------------------------------------------------------------------------
// Kernel 0: transpose x [B,2,H,W,T] -> xT [B,2,T,H,W] so conv reads coalesce.
// ---------------------------------------------------------------------------
__global__ void __launch_bounds__(256) transpose_kernel(
    const float* __restrict__ x, float* __restrict__ xT) {
  __shared__ float tile[64][65];
  int bid   = blockIdx.x;
  int tTile = bid % 6;            // 6 tiles of 64 cover T=350
  int slice = bid / 6;            // (b*2+ci)*64 + h
  int h  = slice % H;
  int bc = slice / H;             // b*2+ci
  int t0 = tTile * 64;
  int tx = threadIdx.x & 63;
  int tz = threadIdx.x >> 6;      // 0..3

  const float* src = x + ((long)bc * H + h) * (long)(W * T);
#pragma unroll
  for (int i = 0; i < 16; ++i) {
    int w = tz * 16 + i;
    int t = t0 + tx;
    tile[w][tx] = (t < T) ? src[(long)w * T + t] : 0.0f;
  }
  __syncthreads();
  float* dst = xT + ((long)bc * T) * HW + h * 64;
#pragma unroll
  for (int i = 0; i < 16; ++i) {
    int tl = tz * 16 + i;
    int t  = t0 + tl;
    if (t < T) dst[(long)t * HW + tx] = tile[tx][tl];
  }
}

// ---------------------------------------------------------------------------
// async global->LDS, 16 bytes per lane (wave-uniform LDS base + lane*16)
// ---------------------------------------------------------------------------
__device__ __forceinline__ void gload_lds16(const float* g, float* l) {
  __builtin_amdgcn_global_load_lds(
      (const __attribute__((address_space(1))) unsigned int*)g,
      (__attribute__((address_space(3))) unsigned int*)l, 16, 0, 0);
}

// ---------------------------------------------------------------------------
// Kernel A: conv1(5x5 over T,H) + bias + relu + LIF1 + delta -> d8 int8
// d8 layout: [b][t][hw][ci]. 2-co-per-thread (r14 verbatim, ~32us):
// block = 512 = (co-pair 0..3) x (h-sub 0..1) x (w 0..63); each thread's 10
// ds_read_b32/step feed 100 FMAs. Grid = B x H/2 x 4 chunks = 256 = 1/CU,
// serial path 105 steps. LDS: 2x32KB input dbuf (S=10) + 10KB st staging.
// ---------------------------------------------------------------------------
__global__ void __launch_bounds__(512) convlif_kernel(
    const float* __restrict__ xT, const float* __restrict__ w1,
    const float* __restrict__ b1, signed char* __restrict__ d8) {
  __shared__ float buf[2][128 * 64];                    // 2 x 32 KiB
  __shared__ __align__(16) unsigned char st[10][1024];  // 10 KiB spikes
  const int tid = threadIdx.x;
  const int bid = blockIdx.x;
  const int chunk = bid & 3;
  const int rest  = bid >> 2;
  const int h2 = rest & 31;                 // h-pair index
  const int b  = rest >> 5;
  const int h0 = h2 * 2;
  const int w  = tid & 63;
  const int hs = (tid >> 6) & 1;            // wave h-sub
  const int cp = tid >> 7;                  // co-pair 0..3
  const int h  = h0 + hs;
  const int wid = tid >> 6;                 // wave id 0..7

  // chunk c of 4 (len 90,90,90,80): stored [90c, te); 15-step warm-up.
  const int tstore = chunk * 90;
  const int ts     = chunk ? tstore - 15 : 0;     // multiple of 5
  const int te     = tstore + 90 < T ? tstore + 90 : T;
  const int nsup   = (te - ts + 9) / 10;

  // Weights for co0=2cp, co1=2cp+1 (VGPR); zero taps with h+dh-2 OOB.
  float wt[2][2][5][5];
#pragma unroll
  for (int ci = 0; ci < 2; ++ci)
#pragma unroll
    for (int dh = 0; dh < 5; ++dh) {
      int hh = h + dh - 2;
      bool hv = (hh >= 0) && (hh < H);
#pragma unroll
      for (int dt = 0; dt < 5; ++dt) {
        wt[0][ci][dt][dh] = hv ? w1[(((cp*2+0) * 2 + ci) * 5 + dt) * 5 + dh] : 0.0f;
        wt[1][ci][dt][dh] = hv ? w1[(((cp*2+1) * 2 + ci) * 5 + dt) * 5 + dh] : 0.0f;
      }
    }
  float bias0 = b1[cp*2], bias1 = b1[cp*2+1];

  // Staging descriptors: 4 issues x 32 rows; row r = j*12 + ci*6 + dhh,
  // dhh in [0,6) covering h rows h0-2..h0+3 (union of both h-subs).
  int cdesc[4];
#pragma unroll
  for (int i = 0; i < 4; ++i) {
    int r = (tid >> 4) + 32 * i;
    if (r > 119) r = 119;                   // clamp SOURCE; dest rows <=127 ok
    int j   = r / 12;
    int rem = r - j * 12;
    int ci  = rem / 6;
    int dhh = rem - ci * 6;
    int hh = h0 + dhh - 2;
    int hc = hh < 0 ? 0 : (hh > H - 1 ? H - 1 : hh);
    cdesc[i] = (((b * 2 + ci) * T) * HW + hc * 64 + (tid & 15) * 4) | (j << 27);
  }

  // Prologue: stage buf[0] (taus ts+3 .. ts+12).
#pragma unroll
  for (int i = 0; i < 4; ++i) {
    int tau = ts + 3 + (cdesc[i] >> 27);
    if (tau > T - 1) tau = T - 1;
    gload_lds16(xT + (long)(cdesc[i] & 0x07ffffff) + (long)tau * HW,
                &buf[0][(i * 32 + wid * 4) * 64]);
  }

  // Window init (taus ts-2..ts+2) from global; slot = tau % 5 (ts%5==0).
  float win[2][5][5];
#pragma unroll
  for (int ci = 0; ci < 2; ++ci)
#pragma unroll
    for (int dh = 0; dh < 5; ++dh) {
      int hh = h + dh - 2;
      int hc = hh < 0 ? 0 : (hh > H - 1 ? H - 1 : hh);
      const float* bp = xT + ((long)((b * 2 + ci) * T)) * HW + hc * 64 + w;
      win[ci][dh][3] = (ts >= 2) ? bp[(long)(ts - 2) * HW] : 0.0f;
      win[ci][dh][4] = (ts >= 1) ? bp[(long)(ts - 1) * HW] : 0.0f;
      win[ci][dh][0] = bp[(long)(ts + 0) * HW];
      win[ci][dh][1] = bp[(long)(ts + 1) * HW];
      win[ci][dh][2] = bp[(long)(ts + 2) * HW];
    }

  asm volatile("s_waitcnt vmcnt(0)" ::: "memory");
  __builtin_amdgcn_s_barrier();
  asm volatile("" ::: "memory");

  signed char* const d8row = d8 + ((long)(b * T)) * (HW * C1) + h0 * 512;
  const int stw = ((hs * 64 + w) * 8 + cp * 2) >> 1;   // ushort index in row

  float y0 = 0.0f, y1 = 0.0f, sp0 = 0.0f, sp1 = 0.0f;
  for (int k = 0; k < nsup; ++k) {
    // barrier1: publish st writes of superstep k-1; next-buf readers done.
    asm volatile("s_waitcnt lgkmcnt(0)" ::: "memory");
    __builtin_amdgcn_s_barrier();
    asm volatile("" ::: "memory");

    // Flush superstep k-1 spikes (stores issued BEFORE staging loads so
    // vmcnt(4) drains them along with buffer-k loads).
    if (k > 0) {
      int tb = ts + 10 * (k - 1);
#pragma unroll
      for (int i = 0; i < 2; ++i) {
        int slot = tid + i * 512;
        if (slot < 640) {
          int u = slot >> 6;
          int c = (slot & 63) * 16;
          int t = tb + u;
          if (t >= tstore && t < te) {
            uint4 v = *reinterpret_cast<const uint4*>(&st[u][c]);
            *reinterpret_cast<uint4*>(d8row + (long)t * (HW * C1) + c) = v;
          }
        }
      }
    }

    if (k + 1 < nsup) {
      int bs = ts + 3 + 10 * (k + 1);
      float* nb = &buf[(k + 1) & 1][0];
#pragma unroll
      for (int i = 0; i < 4; ++i) {
        int tau = bs + (cdesc[i] >> 27);
        if (tau > T - 1) tau = T - 1;
        gload_lds16(xT + (long)(cdesc[i] & 0x07ffffff) + (long)tau * HW,
                    nb + (i * 32 + wid * 4) * 64);
      }
      asm volatile("s_waitcnt vmcnt(4)" ::: "memory");  // buf[k&1]+stores done
    } else {
      asm volatile("s_waitcnt vmcnt(0)" ::: "memory");
    }
    asm volatile("s_waitcnt lgkmcnt(0)" ::: "memory");
    __builtin_amdgcn_s_barrier();           // barrier2: buf[k&1] ready, st free
    asm volatile("" ::: "memory");

    float* lb = &buf[k & 1][0];
    {
      // zero rows whose tau >= T (final supersteps of last chunk only)
      int bufstart = ts + 3 + 10 * k;
      int rz0 = (T - bufstart) * 12;
      if (rz0 < 120) {
        if (rz0 < 0) rz0 = 0;
        for (int r = rz0 + wid; r < 120; r += 8) lb[r * 64 + w] = 0.0f;
        asm volatile("s_waitcnt lgkmcnt(0)" ::: "memory");
        __builtin_amdgcn_s_barrier();
        asm volatile("" ::: "memory");
      }
    }

    const int t0s = ts + 10 * k;
    for (int jj = 0; jj < 2; ++jj) {
#pragma unroll
      for (int u = 0; u < 5; ++u) {
        const int j5 = jj * 5;
        int t = t0s + j5 + u;
        float a0q0 = 0.f, a0q1 = 0.f, a0q2 = 0.f, a0q3 = 0.f;
        float a1q0 = 0.f, a1q1 = 0.f, a1q2 = 0.f, a1q3 = 0.f;
#pragma unroll
        for (int ci = 0; ci < 2; ++ci)
#pragma unroll
          for (int dt = 0; dt < 5; ++dt) {
            const int slot = (u + dt + 3) % 5;
#pragma unroll
            for (int dh = 0; dh < 5; ++dh) {
              const int q = (ci * 25 + dt * 5 + dh) & 3;
              float tap = win[ci][dh][slot];
              float p0 = tap * wt[0][ci][dt][dh];
              float p1 = tap * wt[1][ci][dt][dh];
              if (q == 0)      { a0q0 += p0; a1q0 += p1; }
              else if (q == 1) { a0q1 += p0; a1q1 += p1; }
              else if (q == 2) { a0q2 += p0; a1q2 += p1; }
              else             { a0q3 += p0; a1q3 += p1; }
            }
          }
        float a0 = fmaxf(((a0q0 + a0q1) + (a0q2 + a0q3)) + bias0, 0.0f);
        float a1 = fmaxf(((a1q0 + a1q1) + (a1q2 + a1q3)) + bias1, 0.0f);
        y0 = fmaf(DEC, y0, a0);
        y1 = fmaf(DEC, y1, a1);
        float s0 = (y0 >= 1.0f) ? 1.0f : 0.0f;
        float s1 = (y1 >= 1.0f) ? 1.0f : 0.0f;
        int d0 = (int)(s0 - sp0) & 0xff;
        int d1 = (int)(s1 - sp1) & 0xff;
        unsigned short val = (unsigned short)(d0 | (d1 << 8));
        if (t == 0) val = 0;
        reinterpret_cast<unsigned short*>(&st[j5 + u][0])[stw] = val;
        sp0 = s0; sp1 = s1;
        y0 = (s0 != 0.0f) ? 0.0f : y0;
        y1 = (s1 != 0.0f) ? 0.0f : y1;
        // slide: tau = t+3 at row ((j5+u)*12 + ci*6 + dh + hs)
        const int slot2 = (u + 3) % 5;
#pragma unroll
        for (int ci = 0; ci < 2; ++ci)
#pragma unroll
          for (int dh = 0; dh < 5; ++dh)
            win[ci][dh][slot2] =
                lb[((j5 + u) * 12 + ci * 6 + dh + hs) * 64 + w];
      }
    }
  }

  // Epilogue flush: last superstep's spikes.
  asm volatile("s_waitcnt lgkmcnt(0)" ::: "memory");
  __builtin_amdgcn_s_barrier();
  asm volatile("" ::: "memory");
  {
    int tb = ts + 10 * (nsup - 1);
#pragma unroll
    for (int i = 0; i < 2; ++i) {
      int slot = tid + i * 512;
      if (slot < 640) {
        int u = slot >> 6;
        int c = (slot & 63) * 16;
        int t = tb + u;
        if (t >= tstore && t < te) {
          uint4 v = *reinterpret_cast<const uint4*>(&st[u][c]);
          *reinterpret_cast<uint4*>(d8row + (long)t * (HW * C1) + c) = v;
        }
      }
    }
  }
}

// ---------------------------------------------------------------------------
// Kernel B: deconv(2x2,s2) + bias + relu + conv2(1x1) + LIF2 -> out
// d8 [b][t][hw][ci]: one 8B uint2 load per pair-step, prefetched 1 iter
// ahead. out [B,2,H',W',T']; LDS-staged transposed flush.
// 25 chunks of 28 t' (r10-proven per-wave logic) x 4 WAVES PER BLOCK
// (block 256 = 4 hp x 64 wp, per-wave SB slice): 1600 blocks = 6.25/CU x
// 4 waves = 25 waves/CU resident (64-thr blocks capped packing at ~8-16).
// All 4 waves share (b,chunk) -> identical loop/flush schedule -> the
// __syncthreads() flush barriers stay aligned.
// ---------------------------------------------------------------------------
__global__ void __launch_bounds__(256) stage2_kernel(
    const signed char* __restrict__ d8, const float* __restrict__ dw,
    const float* __restrict__ db, const float* __restrict__ cw,
    const float* __restrict__ cb, float* __restrict__ out) {
  __shared__ float SB[4][2][64][17];        // 34 KiB, one slice per wave
  int bid   = blockIdx.x;
  int chunk = bid % 25;                     // 25 chunks over T'=700
  int rest  = bid / 25;
  int hp4 = rest & 31;                      // h' quad index (HO/4 = 32)
  int b   = rest >> 5;
  int wavei = threadIdx.x >> 6;             // 0..3
  int wp    = threadIdx.x & 63;             // w'
  int hp = hp4 * 4 + wavei;                 // this wave's h'

  int h  = hp >> 1;
  int kh = 1 - (hp & 1);

  float dwk0[2][8], dwk1[2][8];
#pragma unroll
  for (int c = 0; c < 2; ++c)
#pragma unroll
    for (int ci = 0; ci < 8; ++ci) {
      dwk0[c][ci] = dw[((c * 8 + ci) * 2 + 0) * 2 + kh];
      dwk1[c][ci] = dw[((c * 8 + ci) * 2 + 1) * 2 + kh];
    }
  float db0 = db[0], db1 = db[1];
  float cw00 = cw[0], cw01 = cw[1], cw10 = cw[2], cw11 = cw[3];
  float cb0 = cb[0], cb1 = cb[1];

  int t0 = chunk * 28;
  int t1 = t0 + 28;                         // 25*28 = 700 exactly
  int tw = (t0 - 16 > 0) ? t0 - 16 : 0;     // 16-step LIF2 warm-up (even)

  const signed char* dbase = d8 + (((long)b * T) * HW + h * 64 + wp) * C1;
  const long tstride = (long)HW * C1;       // bytes per t
  float* outb = out + ((long)b * 2 * HO) * (long)(WO * TO);

  float y0 = 0.0f, y1 = 0.0f;
  uint2 dc = *reinterpret_cast<const uint2*>(dbase + (long)(tw >> 1) * tstride);
  for (int tp = tw; tp < t1; tp += 2) {
    int tn = (tp + 2 < t1) ? ((tp + 2) >> 1) : ((t1 - 1) >> 1);
    uint2 dn = *reinterpret_cast<const uint2*>(dbase + (long)tn * tstride);

    float dv[8];
#pragma unroll
    for (int ci = 0; ci < 4; ++ci) {
      dv[ci]     = (float)(signed char)((dc.x >> (8 * ci)) & 0xff);
      dv[ci + 4] = (float)(signed char)((dc.y >> (8 * ci)) & 0xff);
    }

#pragma unroll
    for (int par = 0; par < 2; ++par) {     // par=0: tp (kt=1), par=1: tp+1 (kt=0)
      int tpp = tp + par;
      float v0 = db0, v1 = db1;
      if (par == 0) {
#pragma unroll
        for (int ci = 0; ci < 8; ++ci) {
          v0 = fmaf(dv[ci], dwk1[0][ci], v0);
          v1 = fmaf(dv[ci], dwk1[1][ci], v1);
        }
      } else {
#pragma unroll
        for (int ci = 0; ci < 8; ++ci) {
          v0 = fmaf(dv[ci], dwk0[0][ci], v0);
          v1 = fmaf(dv[ci], dwk0[1][ci], v1);
        }
      }
      v0 = fmaxf(v0, 0.0f);
      v1 = fmaxf(v1, 0.0f);
      float u0 = fmaf(cw00, v0, fmaf(cw01, v1, cb0));
      float u1 = fmaf(cw10, v0, fmaf(cw11, v1, cb1));
      y0 = fmaf(DEC, y0, u0);
      y1 = fmaf(DEC, y1, u1);
      float s0 = (y0 >= 1.0f) ? 1.0f : 0.0f;
      float s1 = (y1 >= 1.0f) ? 1.0f : 0.0f;
      y0 = (s0 != 0.0f) ? 0.0f : y0;
      y1 = (s1 != 0.0f) ? 0.0f : y1;

      if (tpp >= t0) {
        int k = (tpp - t0) & 15;
        SB[wavei][0][wp][k] = s0;
        SB[wavei][1][wp][k] = s1;
        if (par == 1 && (k == 15 || tpp == t1 - 1)) {
          __syncthreads();
          int Kc  = k + 1;                  // 16 or 12 (both multiple of 4)
          int t0f = tpp - k;
#pragma unroll
          for (int o = 0; o < 2; ++o) {
            float* ob = outb + ((long)(o * HO + hp)) * (long)(WO * TO);
#pragma unroll
            for (int i = 0; i < 4; ++i) {
              int idx = (i << 6) + wp;
              int r   = idx >> 2;
              int c   = (idx & 3) << 2;
              if (c < Kc) {
                float4 vv;
                vv.x = SB[wavei][o][r][c + 0];
                vv.y = SB[wavei][o][r][c + 1];
                vv.z = SB[wavei][o][r][c + 2];
                vv.w = SB[wavei][o][r][c + 3];
                *reinterpret_cast<float4*>(ob + (long)r * TO + (t0f + c)) = vv;
              }
            }
          }
          __syncthreads();
        }
      }
    }
    dc = dn;
  }
}

// ---------------------------------------------------------------------------
extern "C" void kernel_launch(void* const* d_in, const int* in_sizes, int n_in,
                              void* d_out, int out_size, void* d_ws, size_t ws_size,
                              hipStream_t stream) {
  const float* x  = (const float*)d_in[0];
  const float* w1 = (const float*)d_in[1];
  const float* b1 = (const float*)d_in[2];
  const float* dw = (const float*)d_in[3];
  const float* db = (const float*)d_in[4];
  const float* cw = (const float*)d_in[5];
  const float* cb = (const float*)d_in[6];
  float* out = (float*)d_out;

  float* xT = (float*)d_ws;                                   // 22.94 MB
  signed char* d8 = (signed char*)d_ws + (size_t)B * CIN * T * HW * 4;  // +22.94 MB

  // 1) transpose x -> xT
  transpose_kernel<<<dim3(B * CIN * H * 6), dim3(256), 0, stream>>>(x, xT);
  // 2) conv1+relu+LIF1+delta -> d8 (2-co/thread, 4 chunks, 256 blocks)
  convlif_kernel<<<dim3(B * 32 * 4), dim3(512), 0, stream>>>(xT, w1, b1, d8);
  // 3) deconv+relu+conv2+LIF2 -> out (25 chunks x 4-wave blocks = 25 waves/CU)
  stage2_kernel<<<dim3(B * 32 * 25), dim3(256), 0, stream>>>(d8, dw, db, cw, cb, out);
}